// Round 2
// baseline (185.583 us; speedup 1.0000x reference)
//
#include <hip/hip_runtime.h>
#include <hip/hip_bf16.h>
#include <cstdint>
#include <cstddef>

#define VOCAB 32000
#define HIDDEN 2048
#define NLAYERS 6
#define BATCH 512

// Fused layer GEMM tiling: M=512, N=2048, K=2048
#define BM 64
#define BN 64
#define BK 64
#define NT (HIDDEN / BK)  // 32 K-tiles

typedef __attribute__((ext_vector_type(8))) short bf16x8;
typedef __attribute__((ext_vector_type(4))) float f32x4;

__device__ __forceinline__ unsigned short f2bf(float f) {
  unsigned u = __builtin_bit_cast(unsigned, f);
  u += 0x7fffu + ((u >> 16) & 1u);  // RNE
  return (unsigned short)(u >> 16);
}

__device__ __forceinline__ float tanh_fast(float x) {
  x = fminf(15.f, fmaxf(-15.f, x));
  float e = __expf(2.f * x);
  return (e - 1.f) / (e + 1.f);
}

__device__ __forceinline__ void gload_lds16(const void* g, void* l) {
  __builtin_amdgcn_global_load_lds(
      (const __attribute__((address_space(1))) void*)g,
      (__attribute__((address_space(3))) void*)l, 16, 0, 0);
}

#define WAITV4 asm volatile("s_waitcnt vmcnt(4)" ::: "memory")
#define WAITV2 asm volatile("s_waitcnt vmcnt(2)" ::: "memory")
#define WAITV0 asm volatile("s_waitcnt vmcnt(0)" ::: "memory")

// ---- prep: hh[l] fp32 [K][N] -> Bt bf16 [N][K] (convert + transpose) ----
__global__ __launch_bounds__(256) void k_transpose(const float* __restrict__ hh,
                                                   unsigned short* __restrict__ bt) {
  __shared__ unsigned short tile[64][72];  // padded to dodge bank conflicts
  const int l = blockIdx.z;
  const int n0 = blockIdx.x * 64;
  const int k0 = blockIdx.y * 64;
  const int t = threadIdx.x;
  const float* src = hh + ((size_t)l * HIDDEN + k0) * HIDDEN + n0;
  const int cr = t >> 4;        // 0..15
  const int cc = (t & 15) * 4;  // 0..60
#pragma unroll
  for (int p = 0; p < 4; ++p) {
    const int r = p * 16 + cr;
    float4 v = *(const float4*)(src + (size_t)r * HIDDEN + cc);
    tile[r][cc + 0] = f2bf(v.x);
    tile[r][cc + 1] = f2bf(v.y);
    tile[r][cc + 2] = f2bf(v.z);
    tile[r][cc + 3] = f2bf(v.w);
  }
  __syncthreads();
  const int nl = t >> 2;        // output row (n), 0..63
  const int kk = (t & 3) * 16;  // k chunk
  unsigned short tmp[16] __attribute__((aligned(16)));
#pragma unroll
  for (int j = 0; j < 16; ++j) tmp[j] = tile[kk + j][nl];
  unsigned short* dst = bt + ((size_t)l * HIDDEN + n0 + nl) * HIDDEN + k0 + kk;
  *(uint4*)(dst) = *(const uint4*)(tmp);
  *(uint4*)(dst + 8) = *(const uint4*)(tmp + 8);
}

// ---- prep: initial state fp32 -> bf16 ----
__global__ __launch_bounds__(256) void k_cvt_state(const float* __restrict__ s,
                                                   unsigned short* __restrict__ sb) {
  const int i = (blockIdx.x * 256 + threadIdx.x) * 4;
  float4 v = *(const float4*)(s + i);
  union { unsigned short h[4]; uint2 u; } o;
  o.h[0] = f2bf(v.x); o.h[1] = f2bf(v.y); o.h[2] = f2bf(v.z); o.h[3] = f2bf(v.w);
  *(uint2*)(sb + i) = o.u;
}

// ---- fused layer: C = A(bf16)@Bt^T, then state' = tanh(prev + C*gate) ----
// grid (N/BN=32, M/BM=8), 512 threads = 8 waves (2M x 4N), wave tile 32x16.
__global__ __launch_bounds__(512) void k_layer(const unsigned short* __restrict__ A,
                                               const unsigned short* __restrict__ Bt,
                                               const float* __restrict__ prev,
                                               const float* __restrict__ ihl,
                                               const int* __restrict__ token,
                                               float* __restrict__ outf,
                                               unsigned short* __restrict__ outb) {
  // 3-slot double^H^H triple-buffered LDS, XOR chunk-swizzled (both sides).
  __shared__ __attribute__((aligned(16))) unsigned short As[3][BM][BK];
  __shared__ __attribute__((aligned(16))) unsigned short Bs[3][BN][BK];

  const int n0 = blockIdx.x * BN;
  const int m0 = blockIdx.y * BM;
  const int t = threadIdx.x;
  const int lane = t & 63;
  const int wid = t >> 6;
  const int wm = (wid >> 2) * 32;      // 0 / 32
  const int wn = (wid & 3) * 16;       // 0 / 16 / 32 / 48

  f32x4 zero = {0.f, 0.f, 0.f, 0.f};
  f32x4 acc[2];
  acc[0] = zero; acc[1] = zero;

  // Staging: 512 chunks of 16B per 64x64 bf16 tile; thread t owns chunk t.
  // Global source column is XOR-swizzled by row so that linear LDS + swizzled
  // read is conflict-reduced (16-way -> 2-way).
  const int ch = wid * 64 + lane;
  const int srow = ch >> 3;                         // 0..63
  const int scol = ((ch & 7) ^ (srow & 7)) * 8;     // swizzled k-chunk
  const unsigned short* gA = A + (size_t)(m0 + srow) * HIDDEN + scol;
  const unsigned short* gB = Bt + (size_t)(n0 + srow) * HIDDEN + scol;
  char* lA = (char*)&As[0][0][0] + wid * 1024;
  char* lB = (char*)&Bs[0][0][0] + wid * 1024;

#define STAGE(s, kt)                                            \
  do {                                                          \
    gload_lds16(gA + (kt) * BK, lA + (s) * (BM * BK * 2));      \
    gload_lds16(gB + (kt) * BK, lB + (s) * (BN * BK * 2));      \
  } while (0)

  const int row_a0 = wm + (lane & 15);
  const int row_a1 = row_a0 + 16;
  const int row_b = wn + (lane & 15);
  const int q = lane >> 4;  // 0..3

#define COMPUTE(s)                                                                    \
  do {                                                                                \
    _Pragma("unroll") for (int ks = 0; ks < 2; ++ks) {                                \
      const int cnk = ks * 4 + q;                                                     \
      bf16x8 a0 = *(const bf16x8*)&As[s][row_a0][(cnk ^ (row_a0 & 7)) * 8];           \
      bf16x8 a1 = *(const bf16x8*)&As[s][row_a1][(cnk ^ (row_a1 & 7)) * 8];           \
      bf16x8 b0 = *(const bf16x8*)&Bs[s][row_b][(cnk ^ (row_b & 7)) * 8];             \
      acc[0] = __builtin_amdgcn_mfma_f32_16x16x32_bf16(a0, b0, acc[0], 0, 0, 0);      \
      acc[1] = __builtin_amdgcn_mfma_f32_16x16x32_bf16(a1, b0, acc[1], 0, 0, 0);      \
    }                                                                                 \
  } while (0)

  STAGE(0, 0);
  STAGE(1, 1);
  STAGE(2, 2);

  for (int kt = 0; kt < NT; ++kt) {
    // Guarantee stage kt complete (2 loads/thread per stage, up to 3 in flight).
    if (kt < NT - 2) { WAITV4; } else if (kt == NT - 2) { WAITV2; } else { WAITV0; }
    __builtin_amdgcn_s_barrier();
    __builtin_amdgcn_sched_barrier(0);
    const int s = kt % 3;
    COMPUTE(s);
    __builtin_amdgcn_sched_barrier(0);
    __builtin_amdgcn_s_barrier();
    if (kt + 3 < NT) {
      const int kn = kt + 3;
      STAGE(s, kn);
    }
  }

  // Epilogue: gate gather + residual + tanh, write f32 (+bf16 unless last).
  const int c = n0 + wn + (lane & 15);
#pragma unroll
  for (int fm = 0; fm < 2; ++fm) {
#pragma unroll
    for (int j = 0; j < 4; ++j) {
      const int r = m0 + wm + fm * 16 + q * 4 + j;
      const int tok = token[r];
      const float g = ihl[(size_t)tok * HIDDEN + c];
      const float pv = prev[(size_t)r * HIDDEN + c];
      const float v = tanh_fast(pv + acc[fm][j] * g);
      outf[(size_t)r * HIDDEN + c] = v;
      if (outb) outb[(size_t)r * HIDDEN + c] = f2bf(v);
    }
  }
}

extern "C" void kernel_launch(void* const* d_in, const int* in_sizes, int n_in,
                              void* d_out, int out_size, void* d_ws, size_t ws_size,
                              hipStream_t stream) {
  const float* state = (const float*)d_in[0];
  const int* token = (const int*)d_in[1];
  const float* ih = (const float*)d_in[2];
  const float* hh = (const float*)d_in[3];
  float* out = (float*)d_out;

  // ws layout (16B-aligned):
  //   Bt  : 6*2048*2048 bf16 = 50331648 B
  //   stb : 512*2048 bf16    =  2097152 B
  //   sf  : 512*2048 f32     =  4194304 B
  char* ws = (char*)d_ws;
  unsigned short* bt = (unsigned short*)ws;
  size_t off = (size_t)NLAYERS * HIDDEN * HIDDEN * 2;
  unsigned short* stb = (unsigned short*)(ws + off);
  off += (size_t)BATCH * HIDDEN * 2;
  float* sf = (float*)(ws + off);

  k_transpose<<<dim3(HIDDEN / 64, HIDDEN / 64, NLAYERS), 256, 0, stream>>>(hh, bt);
  k_cvt_state<<<dim3((BATCH * HIDDEN) / 1024), 256, 0, stream>>>(state, stb);

  for (int l = 0; l < NLAYERS; ++l) {
    const bool last = (l == NLAYERS - 1);
    k_layer<<<dim3(HIDDEN / BN, BATCH / BM), 512, 0, stream>>>(
        stb, bt + (size_t)l * HIDDEN * HIDDEN,
        l == 0 ? state : sf,
        ih + (size_t)l * VOCAB * HIDDEN, token,
        last ? out : sf, last ? nullptr : stb);
  }
}